// Round 8
// baseline (576.399 us; speedup 1.0000x reference)
//
#include <hip/hip_runtime.h>

// GADBase guided anisotropic diffusion on MI355X — round 8.
// R6 -> R8: collapse the per-step sync chain (store-drain RTT + flag-store
// RTT + halo-load RTT) into ONE MALL propagation: halo words are packed
// (tag,value) u64s stored fire-and-forget at system scope; consumers poll
// the data words directly with EXACT tag match (state index). No flags, no
// vmcnt drain on the publish path, no buffer zero-init (0xAA poison can't
// match a tag in [1,64)). Parity-slot overwrite safety: producer writes tag
// s into slot s&1 only after staging tag s-1, which required the consumer's
// s-1 publish, which followed the consumer's staging of s-2 -> the tag s-2
// being overwritten was already consumed. Double-buffered LDS tile -> one
// barrier per step. Compute/layout identical to R6 (the 438 us baseline).

#define BB 2
#define HH 1024
#define WW 1024
#define NPIX (HH * WW)
#define CVN (1023 * 1024)
#define CVPN (1025 * 1024)
#define SHW (128 * 128)
#define LL 0.24f
#define KK2 (0.03f * 0.03f)
#define EPSF 1e-8f
#define DEPSF 0.1f
#define NPRE 64
#define NB 512            // persistent grid: 2 per CU on 256 CUs (co-resident)
#define TPB 256

typedef unsigned long long u64;
#define SYS_LD64(p)    __hip_atomic_load((p), __ATOMIC_RELAXED, __HIP_MEMORY_SCOPE_SYSTEM)
#define SYS_ST64(p, v) __hip_atomic_store((p), (v), __ATOMIC_RELAXED, __HIP_MEMORY_SCOPE_SYSTEM)

__device__ inline u64 pk(float v, unsigned tag) {
    return ((u64)tag << 32) | (u64)__float_as_uint(v);
}
__device__ inline float pv(u64 w) { return __uint_as_float((unsigned)w); }
__device__ inline unsigned pt(u64 w) { return (unsigned)(w >> 32); }

__global__ void setup_kernel(const float* __restrict__ src, float* __restrict__ shiftOut) {
    int tid = threadIdx.x;
    float m = 1e30f;
    for (int i = tid; i < BB * SHW; i += TPB) m = fminf(m, src[i]);
    for (int off = 32; off > 0; off >>= 1) m = fminf(m, __shfl_down(m, off));
    __shared__ float sm[4];
    if ((tid & 63) == 0) sm[tid >> 6] = m;
    __syncthreads();
    if (tid == 0) {
        float mm = fminf(fminf(sm[0], sm[1]), fminf(sm[2], sm[3]));
        shiftOut[0] = (mm <= DEPSF) ? DEPSF : 0.0f;
    }
}

__global__ void init_kernel(const float* __restrict__ guide, const float* __restrict__ yb,
                            const float* __restrict__ shiftPtr, float* __restrict__ img0,
                            float* __restrict__ cv_out, float* __restrict__ ch_out,
                            float* __restrict__ cvp, float* __restrict__ chp) {
    int idx = blockIdx.x * blockDim.x + threadIdx.x;
    if (idx >= BB * NPIX) return;
    int b = idx >> 20;
    int p = idx & (NPIX - 1);
    int y = p >> 10;
    int x = p & 1023;
    const float* gb = guide + (size_t)b * 3 * NPIX;
    const float* yBb = yb + (size_t)b * NPIX;
    float c0 = yBb[p];
    img0[(size_t)b * NPIX + p] = c0 + shiftPtr[0];
    // shift cancels in finite diffs -> cv/ch from raw y_bicubic.
    float* cvpb = cvp + (size_t)b * CVPN;
    float* chpb = chp + (size_t)b * NPIX;
    if (y < HH - 1) {
        float d = fabsf(gb[p + WW] - gb[p])
                + fabsf(gb[NPIX + p + WW] - gb[NPIX + p])
                + fabsf(gb[2 * NPIX + p + WW] - gb[2 * NPIX + p])
                + fabsf(yBb[p + WW] - c0);
        d *= 0.25f;
        float v = 1.0f / (1.0f + (d * d) / KK2);
        cv_out[(size_t)b * CVN + y * WW + x] = v;
        cvpb[(y + 1) * WW + x] = v;           // padded: row r holds cv[r-1]
    } else {
        cvpb[x] = 0.f;
        cvpb[1024 * WW + x] = 0.f;
    }
    if (x < WW - 1) {
        float d = fabsf(gb[p + 1] - gb[p])
                + fabsf(gb[NPIX + p + 1] - gb[NPIX + p])
                + fabsf(gb[2 * NPIX + p + 1] - gb[2 * NPIX + p])
                + fabsf(yBb[p + 1] - c0);
        d *= 0.25f;
        float v = 1.0f / (1.0f + (d * d) / KK2);
        ch_out[(size_t)b * CVN + y * 1023 + x] = v;
        chpb[y * WW + x] = v;                 // padded stride-1024, col 1023 = 0
    } else {
        chpb[y * WW + 1023] = 0.f;
    }
}

#define TL(P, i, j) P[(i) * 132 + (j)]

__launch_bounds__(TPB, 2)
__global__ void persist_kernel(const float* __restrict__ img0, float* __restrict__ out,
                               const float* __restrict__ cvp, const float* __restrict__ chp,
                               const float* __restrict__ src, const float* __restrict__ mask,
                               const float* __restrict__ shiftPtr,
                               u64* __restrict__ bufRow, u64* __restrict__ bufCol) {
    __shared__ float imt[2][34 * 132];
    int blk = blockIdx.x;
    int b = blk >> 8;
    int r = blk & 255;
    int tileY = r >> 3;          // 0..31
    int tileX = r & 7;           // 0..7
    int tid = threadIdx.x;
    int cyL = tid >> 5;          // 0..7
    int g = tid & 31;            // 0..31
    int lx0 = g * 4;
    int ly0 = cyL * 4;
    int gx = tileX * 128 + lx0;
    int gy = tileY * 32 + ly0;

    const float* im0 = img0 + (size_t)b * NPIX;
    const float* cvpb = cvp + (size_t)b * CVPN;
    const float* chpb = chp + (size_t)b * NPIX;
    float shift = shiftPtr[0];

    // conductances resident in registers for all 64 steps
    float4 cvR[5], chR[4];
    float hmR[4];
#pragma unroll
    for (int j = 0; j < 5; ++j)
        cvR[j] = *(const float4*)(cvpb + (size_t)(gy + j) * WW + gx);
#pragma unroll
    for (int k = 0; k < 4; ++k) {
        chR[k] = *(const float4*)(chpb + (size_t)(gy + k) * WW + gx);
        hmR[k] = (gx > 0) ? chpb[(size_t)(gy + k) * WW + gx - 1] : 0.f;
    }
    int sy = tileY * 4 + (cyL >> 1);
    int sx = tileX * 16 + (g >> 1);
    int sidx = b * SHW + sy * 128 + sx;
    float sval = src[sidx] + shift;
    bool masked = mask[sidx] < 0.5f;

    float* cur = &imt[0][0];
    float* nxt = &imt[1][0];

    // role predicates + halo buffer addresses (hoisted; par-dependent offset
    // added in-loop). Row role: stage row halo. Col role: stage col halo.
    bool rAct = (cyL == 0 && tileY > 0) || (cyL == 7 && tileY < 31);
    const u64* rBase = nullptr; int rDst = 0;
    if (cyL == 0) { rBase = &bufRow[(((size_t)blk - 8) * 2 + 1) * 128 + lx0]; rDst = 0; }
    if (cyL == 7) { rBase = &bufRow[(((size_t)blk + 8) * 2 + 0) * 128 + lx0]; rDst = 33; }
    bool cAct = (g == 0 && tileX > 0) || (g == 31 && tileX < 7);
    const u64* cBase = nullptr; int cDst = 0;
    if (g == 0)  { cBase = &bufCol[(((size_t)blk - 1) * 2 + 1) * 32 + ly0]; cDst = 0; }
    if (g == 31) { cBase = &bufCol[(((size_t)blk + 1) * 2 + 0) * 32 + ly0]; cDst = 129; }
    const size_t rowPar = (size_t)NB * 2 * 128;   // u64 elems per parity plane
    const size_t colPar = (size_t)NB * 2 * 32;

    // initial fill of cur (interior + halos). Boundary halos (image edges,
    // matching conductance == 0) are written into BOTH buffers since they
    // are never re-staged; interior halos are staged into nxt each step.
#pragma unroll
    for (int k = 0; k < 4; ++k)
        *(float4*)&TL(cur, 1 + ly0 + k, 1 + lx0) =
            *(const float4*)(im0 + (size_t)(gy + k) * WW + gx);
    float4 z4 = make_float4(0.f, 0.f, 0.f, 0.f);
    if (cyL == 0) {
        if (tileY > 0) {
            *(float4*)&TL(cur, 0, 1 + lx0) = *(const float4*)(im0 + (size_t)(gy - 1) * WW + gx);
        } else {
            *(float4*)&TL(cur, 0, 1 + lx0) = z4;
            *(float4*)&TL(nxt, 0, 1 + lx0) = z4;
        }
    }
    if (cyL == 7) {
        if (tileY < 31) {
            *(float4*)&TL(cur, 33, 1 + lx0) = *(const float4*)(im0 + (size_t)(gy + 4) * WW + gx);
        } else {
            *(float4*)&TL(cur, 33, 1 + lx0) = z4;
            *(float4*)&TL(nxt, 33, 1 + lx0) = z4;
        }
    }
    if (g == 0) {
#pragma unroll
        for (int k = 0; k < 4; ++k) {
            float v = (tileX > 0) ? im0[(size_t)(gy + k) * WW + gx - 1] : 0.f;
            TL(cur, 1 + ly0 + k, 0) = v;
            if (tileX == 0) TL(nxt, 1 + ly0 + k, 0) = 0.f;
        }
    }
    if (g == 31) {
#pragma unroll
        for (int k = 0; k < 4; ++k) {
            float v = (tileX < 7) ? im0[(size_t)(gy + k) * WW + gx + 4] : 0.f;
            TL(cur, 1 + ly0 + k, 129) = v;
            if (tileX == 7) TL(nxt, 1 + ly0 + k, 129) = 0.f;
        }
    }
    __syncthreads();

    float4 nv[4];
    for (int t = 0; t < NPRE; ++t) {
        // ---- diffuse + adjust: state t (cur) -> nv = state t+1 ----
        float4 rUp = *(float4*)&TL(cur, ly0, 1 + lx0);
        float4 rC  = *(float4*)&TL(cur, ly0 + 1, 1 + lx0);
        float csum = 0.f;
#pragma unroll
        for (int k = 0; k < 4; ++k) {
            float4 rDn = *(float4*)&TL(cur, ly0 + 2 + k, 1 + lx0);
            float4 cu = cvR[k], cd = cvR[k + 1], h4 = chR[k];
            float xl = __shfl_up(rC.w, 1);
            float xr = __shfl_down(rC.x, 1);
            float hm = hmR[k];
            if (g == 0)  xl = TL(cur, 1 + ly0 + k, 0);
            if (g == 31) xr = TL(cur, 1 + ly0 + k, 129);
            float4 acc;
            acc.x = rC.x + LL * (cd.x * (rDn.x - rC.x) - cu.x * (rC.x - rUp.x)
                               + h4.x * (rC.y - rC.x) - hm   * (rC.x - xl));
            acc.y = rC.y + LL * (cd.y * (rDn.y - rC.y) - cu.y * (rC.y - rUp.y)
                               + h4.y * (rC.z - rC.y) - h4.x * (rC.y - rC.x));
            acc.z = rC.z + LL * (cd.z * (rDn.z - rC.z) - cu.z * (rC.z - rUp.z)
                               + h4.z * (rC.w - rC.z) - h4.y * (rC.z - rC.y));
            acc.w = rC.w + LL * (cd.w * (rDn.w - rC.w) - cu.w * (rC.w - rUp.w)
                               + h4.w * (xr   - rC.w) - h4.z * (rC.w - rC.z));
            nv[k] = acc;
            csum += acc.x + acc.y + acc.z + acc.w;
            rUp = rC; rC = rDn;
        }
        csum += __shfl_xor(csum, 1);
        csum += __shfl_xor(csum, 32);   // 8x8 cell = lanes {tid,tid^1,tid^32,tid^33}
        float ratio = masked ? 1.0f : sval / (csum * (1.0f / 64.0f) + EPSF);
#pragma unroll
        for (int k = 0; k < 4; ++k) {
            nv[k].x *= ratio; nv[k].y *= ratio; nv[k].z *= ratio; nv[k].w *= ratio;
        }

        if (t == NPRE - 1) break;
        unsigned s = (unsigned)(t + 1);          // state index being exchanged
        size_t rOff = (s & 1) ? rowPar : 0;      // parity slot
        size_t cOff = (s & 1) ? colPar : 0;

        // ---- publish tagged edges: fire-and-forget system-scope u64 stores ----
        if (cyL == 0) {
            u64* p = &bufRow[rOff + ((size_t)blk * 2 + 0) * 128 + lx0];
            SYS_ST64(p + 0, pk(nv[0].x, s)); SYS_ST64(p + 1, pk(nv[0].y, s));
            SYS_ST64(p + 2, pk(nv[0].z, s)); SYS_ST64(p + 3, pk(nv[0].w, s));
        }
        if (cyL == 7) {
            u64* p = &bufRow[rOff + ((size_t)blk * 2 + 1) * 128 + lx0];
            SYS_ST64(p + 0, pk(nv[3].x, s)); SYS_ST64(p + 1, pk(nv[3].y, s));
            SYS_ST64(p + 2, pk(nv[3].z, s)); SYS_ST64(p + 3, pk(nv[3].w, s));
        }
        if (g == 0) {
            u64* p = &bufCol[cOff + ((size_t)blk * 2 + 0) * 32 + ly0];
#pragma unroll
            for (int k = 0; k < 4; ++k) SYS_ST64(p + k, pk(nv[k].x, s));
        }
        if (g == 31) {
            u64* p = &bufCol[cOff + ((size_t)blk * 2 + 1) * 32 + ly0];
#pragma unroll
            for (int k = 0; k < 4; ++k) SYS_ST64(p + k, pk(nv[k].w, s));
        }

        // ---- interior of state t+1 into nxt (overlaps store flight) ----
#pragma unroll
        for (int k = 0; k < 4; ++k)
            *(float4*)&TL(nxt, 1 + ly0 + k, 1 + lx0) = nv[k];

        // ---- stage neighbor halos: poll tagged words until tag == s ----
        if (rAct) {
            const u64* p = rBase + rOff;
            u64 a0, a1, a2, a3;
            for (;;) {
                a0 = SYS_LD64(p + 0); a1 = SYS_LD64(p + 1);
                a2 = SYS_LD64(p + 2); a3 = SYS_LD64(p + 3);
                if (pt(a0) == s && pt(a1) == s && pt(a2) == s && pt(a3) == s) break;
                __builtin_amdgcn_s_sleep(1);
            }
            TL(nxt, rDst, 1 + lx0 + 0) = pv(a0);
            TL(nxt, rDst, 1 + lx0 + 1) = pv(a1);
            TL(nxt, rDst, 1 + lx0 + 2) = pv(a2);
            TL(nxt, rDst, 1 + lx0 + 3) = pv(a3);
        }
        if (cAct) {
            const u64* p = cBase + cOff;
            u64 a0, a1, a2, a3;
            for (;;) {
                a0 = SYS_LD64(p + 0); a1 = SYS_LD64(p + 1);
                a2 = SYS_LD64(p + 2); a3 = SYS_LD64(p + 3);
                if (pt(a0) == s && pt(a1) == s && pt(a2) == s && pt(a3) == s) break;
                __builtin_amdgcn_s_sleep(1);
            }
            TL(nxt, 1 + ly0 + 0, cDst) = pv(a0);
            TL(nxt, 1 + ly0 + 1, cDst) = pv(a1);
            TL(nxt, 1 + ly0 + 2, cDst) = pv(a2);
            TL(nxt, 1 + ly0 + 3, cDst) = pv(a3);
        }

        __syncthreads();   // single barrier per step: nxt fully built
        float* tmp = cur; cur = nxt; nxt = tmp;
    }

    // final output: state 64 - shift, straight from registers
    float* ob = out + (size_t)b * NPIX;
#pragma unroll
    for (int k = 0; k < 4; ++k) {
        float4 v = nv[k];
        v.x -= shift; v.y -= shift; v.z -= shift; v.w -= shift;
        *(float4*)(ob + (size_t)(gy + k) * WW + gx) = v;
    }
}

extern "C" void kernel_launch(void* const* d_in, const int* in_sizes, int n_in,
                              void* d_out, int out_size, void* d_ws, size_t ws_size,
                              hipStream_t stream) {
    const float* guide = (const float*)d_in[0];   // [2,3,1024,1024]
    const float* yb    = (const float*)d_in[1];   // [2,1,1024,1024]
    const float* src   = (const float*)d_in[2];   // [2,1,128,128]
    const float* mask  = (const float*)d_in[3];   // [2,1,128,128]

    float* out    = (float*)d_out;                       // y_pred [2,1,1024,1024]
    float* out_cv = out + (size_t)BB * NPIX;
    float* out_ch = out_cv + (size_t)BB * CVN;

    float* wsf = (float*)d_ws;
    float* shift = wsf;                                  // [256] slot
    float* imgA = wsf + 256;                             // init image, 2*NPIX
    float* cvp  = imgA + (size_t)BB * NPIX;              // 2*1025*1024
    float* chp  = cvp + (size_t)BB * CVPN;               // 2*1024*1024
    u64* bufRow = (u64*)(chp + (size_t)BB * NPIX);       // 2 par x 512 x 2 x 128 u64
    u64* bufCol = bufRow + (size_t)2 * NB * 2 * 128;     // 2 par x 512 x 2 x 32 u64

    setup_kernel<<<1, TPB, 0, stream>>>(src, shift);
    init_kernel<<<(BB * NPIX) / TPB, TPB, 0, stream>>>(guide, yb, shift, imgA,
                                                       out_cv, out_ch, cvp, chp);

    persist_kernel<<<NB, TPB, 0, stream>>>(imgA, out, cvp, chp, src, mask, shift,
                                           bufRow, bufCol);
}